// Round 1
// baseline (421.364 us; speedup 1.0000x reference)
//
#include <hip/hip_runtime.h>

typedef __attribute__((ext_vector_type(8))) short bf16x8;
typedef __attribute__((ext_vector_type(4))) float floatx4;

constexpr int BATCH = 4;
constexpr int SEQ   = 2048;
constexpr int DIMN  = 1024;
constexpr int M1    = BATCH * SEQ; // 8192

constexpr int BM = 128, BN = 128, BK = 32;
constexpr int LDSK = BK + 8; // +8 bf16 pad to break LDS bank aliasing

__device__ __forceinline__ short f2bf(float f) {
    union { float f; unsigned u; } x; x.f = f;
    unsigned r = x.u + 0x7fffu + ((x.u >> 16) & 1u); // RNE
    return (short)(r >> 16);
}
__device__ __forceinline__ float bf2f(short s) {
    union { unsigned u; float f; } x; x.u = ((unsigned)(unsigned short)s) << 16;
    return x.f;
}

// ---------------------------------------------------------------------------
// Projection GEMM: out = (X [+ctx]) @ W^T + bias, fp32 inputs, bf16 output.
// X: [M1, DIMN] fp32, W: [DIMN, DIMN] fp32 (row-major [N,K]), bias: [DIMN].
// TRANS_OUT: write out[b][n][s] (v^T layout) instead of out[m][n].
// ---------------------------------------------------------------------------
template<bool ADD_CTX, bool TRANS_OUT>
__global__ __launch_bounds__(256)
void proj_kernel(const float* __restrict__ X, const float* __restrict__ W,
                 const float* __restrict__ bias, const float* __restrict__ ctx,
                 short* __restrict__ out)
{
    __shared__ short As[BM][LDSK];
    __shared__ short Bs[BN][LDSK];
    const int m0 = blockIdx.y * BM;
    const int n0 = blockIdx.x * BN;
    const int tid  = threadIdx.x;
    const int lane = tid & 63;
    const int wave = tid >> 6;
    const int wr = wave >> 1, wc = wave & 1;
    const int lr = lane & 15;       // row/col within 16
    const int lq = lane >> 4;       // quad 0..3

    floatx4 acc[4][4];
    #pragma unroll
    for (int i = 0; i < 4; ++i)
        #pragma unroll
        for (int j = 0; j < 4; ++j) acc[i][j] = (floatx4)(0.f);

    for (int k0 = 0; k0 < DIMN; k0 += BK) {
        __syncthreads();
        #pragma unroll
        for (int h = 0; h < 2; ++h) {
            const int c   = tid + h * 256;
            const int row = c >> 2;
            const int kc  = (c & 3) * 8;
            const float* pa = X + (size_t)(m0 + row) * DIMN + k0 + kc;
            const float4 a0 = *(const float4*)pa;
            const float4 a1 = *(const float4*)(pa + 4);
            float va[8] = {a0.x, a0.y, a0.z, a0.w, a1.x, a1.y, a1.z, a1.w};
            if (ADD_CTX) {
                #pragma unroll
                for (int j = 0; j < 8; ++j) va[j] += ctx[k0 + kc + j];
            }
            bf16x8 av;
            #pragma unroll
            for (int j = 0; j < 8; ++j) av[j] = f2bf(va[j]);
            *(bf16x8*)&As[row][kc] = av;

            const float* pb = W + (size_t)(n0 + row) * DIMN + k0 + kc;
            const float4 b0 = *(const float4*)pb;
            const float4 b1 = *(const float4*)(pb + 4);
            float vb[8] = {b0.x, b0.y, b0.z, b0.w, b1.x, b1.y, b1.z, b1.w};
            bf16x8 bv;
            #pragma unroll
            for (int j = 0; j < 8; ++j) bv[j] = f2bf(vb[j]);
            *(bf16x8*)&Bs[row][kc] = bv;
        }
        __syncthreads();
        bf16x8 af[4], bfr[4];
        #pragma unroll
        for (int i = 0; i < 4; ++i)
            af[i] = *(const bf16x8*)&As[wr * 64 + i * 16 + lr][lq * 8];
        #pragma unroll
        for (int j = 0; j < 4; ++j)
            bfr[j] = *(const bf16x8*)&Bs[wc * 64 + j * 16 + lr][lq * 8];
        #pragma unroll
        for (int i = 0; i < 4; ++i)
            #pragma unroll
            for (int j = 0; j < 4; ++j)
                acc[i][j] = __builtin_amdgcn_mfma_f32_16x16x32_bf16(
                    af[i], bfr[j], acc[i][j], 0, 0, 0);
    }

    // Epilogue: D layout col=lane&15, row=(lane>>4)*4+r  [m89-verified]
    #pragma unroll
    for (int j = 0; j < 4; ++j) {
        const int gn = n0 + wc * 64 + j * 16 + lr;
        const float bv = bias[gn];
        #pragma unroll
        for (int i = 0; i < 4; ++i) {
            #pragma unroll
            for (int r = 0; r < 4; ++r) {
                const int gm = m0 + wr * 64 + i * 16 + lq * 4 + r;
                const float v = acc[i][j][r] + bv;
                if (TRANS_OUT) {
                    const int b = gm >> 11;          // / SEQ
                    const int s = gm & (SEQ - 1);    // % SEQ
                    out[(size_t)b * DIMN * SEQ + (size_t)gn * SEQ + s] = f2bf(v);
                } else {
                    out[(size_t)gm * DIMN + gn] = f2bf(v);
                }
            }
        }
    }
}

// ---------------------------------------------------------------------------
// Batched bf16 A @ B^T GEMM. A: [*, lda] bf16, B: [*, ldb] bf16 (B^T form).
// OUT_BF16: C bf16 with scale applied; else C fp32.
// ---------------------------------------------------------------------------
template<bool OUT_BF16>
__global__ __launch_bounds__(256)
void gemm_bt_bf16(const short* __restrict__ A, size_t sA, int lda,
                  const short* __restrict__ Bm, size_t sB, int ldb,
                  void* __restrict__ C, size_t sC, int ldc,
                  int K, float scale)
{
    __shared__ short As[BM][LDSK];
    __shared__ short Bs[BN][LDSK];
    const int bz = blockIdx.z;
    const short* Ab = A  + (size_t)bz * sA;
    const short* Bb = Bm + (size_t)bz * sB;
    const int m0 = blockIdx.y * BM;
    const int n0 = blockIdx.x * BN;
    const int tid  = threadIdx.x;
    const int lane = tid & 63;
    const int wave = tid >> 6;
    const int wr = wave >> 1, wc = wave & 1;
    const int lr = lane & 15;
    const int lq = lane >> 4;

    floatx4 acc[4][4];
    #pragma unroll
    for (int i = 0; i < 4; ++i)
        #pragma unroll
        for (int j = 0; j < 4; ++j) acc[i][j] = (floatx4)(0.f);

    for (int k0 = 0; k0 < K; k0 += BK) {
        __syncthreads();
        #pragma unroll
        for (int h = 0; h < 2; ++h) {
            const int c   = tid + h * 256;
            const int row = c >> 2;
            const int kc  = (c & 3) * 8;
            *(bf16x8*)&As[row][kc] =
                *(const bf16x8*)(Ab + (size_t)(m0 + row) * lda + k0 + kc);
            *(bf16x8*)&Bs[row][kc] =
                *(const bf16x8*)(Bb + (size_t)(n0 + row) * ldb + k0 + kc);
        }
        __syncthreads();
        bf16x8 af[4], bfr[4];
        #pragma unroll
        for (int i = 0; i < 4; ++i)
            af[i] = *(const bf16x8*)&As[wr * 64 + i * 16 + lr][lq * 8];
        #pragma unroll
        for (int j = 0; j < 4; ++j)
            bfr[j] = *(const bf16x8*)&Bs[wc * 64 + j * 16 + lr][lq * 8];
        #pragma unroll
        for (int i = 0; i < 4; ++i)
            #pragma unroll
            for (int j = 0; j < 4; ++j)
                acc[i][j] = __builtin_amdgcn_mfma_f32_16x16x32_bf16(
                    af[i], bfr[j], acc[i][j], 0, 0, 0);
    }

    #pragma unroll
    for (int j = 0; j < 4; ++j) {
        const int gn = n0 + wc * 64 + j * 16 + lr;
        #pragma unroll
        for (int i = 0; i < 4; ++i) {
            #pragma unroll
            for (int r = 0; r < 4; ++r) {
                const int gm = m0 + wr * 64 + i * 16 + lq * 4 + r;
                const float v = acc[i][j][r] * scale;
                if (OUT_BF16) {
                    ((short*)C)[(size_t)bz * sC + (size_t)gm * ldc + gn] = f2bf(v);
                } else {
                    ((float*)C)[(size_t)bz * sC + (size_t)gm * ldc + gn] = v;
                }
            }
        }
    }
}

// ---------------------------------------------------------------------------
// Row softmax, in place on bf16 [M1 rows][SEQ]. fp32 math.
// ---------------------------------------------------------------------------
__global__ __launch_bounds__(256)
void softmax_kernel(short* __restrict__ P)
{
    const int row  = blockIdx.x;
    short* p = P + (size_t)row * SEQ;
    const int t    = threadIdx.x;
    const int lane = t & 63;
    const int wave = t >> 6;
    __shared__ float red[8];

    bf16x8 raw = *(const bf16x8*)(p + t * 8);
    float v[8];
    float mx = -1e30f;
    #pragma unroll
    for (int j = 0; j < 8; ++j) { v[j] = bf2f(raw[j]); mx = fmaxf(mx, v[j]); }
    #pragma unroll
    for (int off = 32; off > 0; off >>= 1) mx = fmaxf(mx, __shfl_xor(mx, off));
    if (lane == 0) red[wave] = mx;
    __syncthreads();
    mx = fmaxf(fmaxf(red[0], red[1]), fmaxf(red[2], red[3]));

    float e[8], s = 0.f;
    #pragma unroll
    for (int j = 0; j < 8; ++j) { e[j] = __expf(v[j] - mx); s += e[j]; }
    #pragma unroll
    for (int off = 32; off > 0; off >>= 1) s += __shfl_xor(s, off);
    if (lane == 0) red[4 + wave] = s;
    __syncthreads();
    s = red[4] + red[5] + red[6] + red[7];
    const float inv = 1.f / s;

    bf16x8 o;
    #pragma unroll
    for (int j = 0; j < 8; ++j) o[j] = f2bf(e[j] * inv);
    *(bf16x8*)(p + t * 8) = o;
}

// ---------------------------------------------------------------------------
extern "C" void kernel_launch(void* const* d_in, const int* in_sizes, int n_in,
                              void* d_out, int out_size, void* d_ws, size_t ws_size,
                              hipStream_t stream)
{
    const float* query = (const float*)d_in[0];
    const float* key_  = (const float*)d_in[1];
    const float* value = (const float*)d_in[2];
    const float* ctx   = (const float*)d_in[3];
    const float* Wq    = (const float*)d_in[4];
    const float* bq    = (const float*)d_in[5];
    const float* Wk    = (const float*)d_in[6];
    const float* bk    = (const float*)d_in[7];
    const float* Wv    = (const float*)d_in[8];
    const float* bv    = (const float*)d_in[9];

    // Workspace layout (bf16 shorts): q_b, k_b: [M1, DIMN]; v_t: [B][DIMN][SEQ];
    // S_b: [B][SEQ][SEQ].  Total 84 MB.
    short* q_b = (short*)d_ws;
    short* k_b = q_b + (size_t)M1 * DIMN;
    short* v_t = k_b + (size_t)M1 * DIMN;
    short* S_b = v_t + (size_t)M1 * DIMN;

    dim3 blk(256);
    proj_kernel<true,  false><<<dim3(DIMN / BN, M1 / BM), blk, 0, stream>>>(query, Wq, bq, ctx, q_b);
    proj_kernel<true,  false><<<dim3(DIMN / BN, M1 / BM), blk, 0, stream>>>(key_,  Wk, bk, ctx, k_b);
    proj_kernel<false, true ><<<dim3(DIMN / BN, M1 / BM), blk, 0, stream>>>(value, Wv, bv, nullptr, v_t);

    const float scale = 1.0f / 32.0f; // DIMN^-0.5
    gemm_bt_bf16<true><<<dim3(SEQ / BN, SEQ / BM, BATCH), blk, 0, stream>>>(
        q_b, (size_t)SEQ * DIMN, DIMN,
        k_b, (size_t)SEQ * DIMN, DIMN,
        S_b, (size_t)SEQ * SEQ, SEQ, DIMN, scale);

    softmax_kernel<<<dim3(M1), blk, 0, stream>>>(S_b);

    gemm_bt_bf16<false><<<dim3(DIMN / BN, SEQ / BM, BATCH), blk, 0, stream>>>(
        S_b, (size_t)SEQ * SEQ, SEQ,
        v_t, (size_t)DIMN * SEQ, SEQ,
        d_out, (size_t)SEQ * DIMN, DIMN, SEQ, 1.0f);
}

// Round 2
// 415.684 us; speedup vs baseline: 1.0137x; 1.0137x over previous
//
#include <hip/hip_runtime.h>

typedef __attribute__((ext_vector_type(8))) short bf16x8;
typedef __attribute__((ext_vector_type(4))) float floatx4;

constexpr int BATCH = 4;
constexpr int SEQ   = 2048;
constexpr int DIMN  = 1024;
constexpr int M1    = BATCH * SEQ; // 8192

constexpr int BM = 128, BN = 128, BK = 32;

__device__ __forceinline__ short f2bf(float f) {
    union { float f; unsigned u; } x; x.f = f;
    unsigned r = x.u + 0x7fffu + ((x.u >> 16) & 1u); // RNE
    return (short)(r >> 16);
}
__device__ __forceinline__ float bf2f(short s) {
    union { unsigned u; float f; } x; x.u = ((unsigned)(unsigned short)s) << 16;
    return x.f;
}

// async 16-byte global -> LDS copy (gfx950). LDS dest must be
// wave-uniform base + lane*16 — our staging layout guarantees this.
__device__ __forceinline__ void async16(const void* g, void* l) {
    __builtin_amdgcn_global_load_lds(
        (const __attribute__((address_space(1))) unsigned int*)g,
        (__attribute__((address_space(3))) unsigned int*)l, 16, 0, 0);
}

// ---------------------------------------------------------------------------
// fp32 -> bf16 bulk convert. n8 = element count / 8.
// ---------------------------------------------------------------------------
__global__ __launch_bounds__(256)
void cvt_bf16(const float* __restrict__ in, short* __restrict__ out, int n8)
{
    const int i = blockIdx.x * 256 + threadIdx.x;
    if (i >= n8) return;
    const float4 a0 = ((const float4*)in)[(size_t)i * 2];
    const float4 a1 = ((const float4*)in)[(size_t)i * 2 + 1];
    const float v[8] = {a0.x, a0.y, a0.z, a0.w, a1.x, a1.y, a1.z, a1.w};
    bf16x8 o;
    #pragma unroll
    for (int j = 0; j < 8; ++j) o[j] = f2bf(v[j]);
    *(bf16x8*)(out + (size_t)i * 8) = o;
}

// ---------------------------------------------------------------------------
// Effective bias: out[n] = b[n] + dot(ctx, W[n,:])  (fp32; ctx may be null).
// One wave per output row; grid = DIMN/4 blocks of 256.
// ---------------------------------------------------------------------------
__global__ __launch_bounds__(256)
void bias_ctx(const float* __restrict__ W, const float* __restrict__ b,
              const float* __restrict__ ctx, float* __restrict__ out)
{
    const int n    = blockIdx.x * 4 + (threadIdx.x >> 6);
    const int lane = threadIdx.x & 63;
    float s = 0.f;
    if (ctx) {
        const float* row = W + (size_t)n * DIMN;
        for (int k = lane * 4; k < DIMN; k += 256) {
            const float4 x = *(const float4*)(row + k);
            const float4 c = *(const float4*)(ctx + k);
            s += x.x * c.x + x.y * c.y + x.z * c.z + x.w * c.w;
        }
        #pragma unroll
        for (int off = 32; off > 0; off >>= 1) s += __shfl_xor(s, off);
    }
    if (lane == 0) out[n] = b[n] + s;
}

// ---------------------------------------------------------------------------
// bf16 transpose: in [B][S][D] -> out [B][D][S], 64x64 LDS tiles.
// ---------------------------------------------------------------------------
__global__ __launch_bounds__(256)
void transpose_v(const short* __restrict__ in, short* __restrict__ out)
{
    __shared__ short t[64][68];
    const int b  = blockIdx.z;
    const int d0 = blockIdx.x * 64;
    const int s0 = blockIdx.y * 64;
    const int r  = threadIdx.x >> 3;        // 0..31
    const int c  = (threadIdx.x & 7) * 8;   // 0..56
    #pragma unroll
    for (int h = 0; h < 2; ++h) {
        const int s = r + h * 32;
        bf16x8 v = *(const bf16x8*)(in + ((size_t)b * SEQ + s0 + s) * DIMN + d0 + c);
        #pragma unroll
        for (int j = 0; j < 8; ++j) t[c + j][s] = v[j];
    }
    __syncthreads();
    #pragma unroll
    for (int h = 0; h < 2; ++h) {
        const int d = r + h * 32;
        bf16x8 v;
        #pragma unroll
        for (int j = 0; j < 8; ++j) v[j] = t[d][c + j];
        *(bf16x8*)(out + ((size_t)b * DIMN + d0 + d) * SEQ + s0 + c) = v;
    }
}

// ---------------------------------------------------------------------------
// bf16 A @ B^T GEMM, global_load_lds(16B) staging, 128x128x32 tiles.
// A: [*, lda] bf16, B(=B^T form): [*, ldb] bf16. Optional fp32 bias[gn].
// OUT_BF16: C bf16 (scale applied); else C fp32.
// ---------------------------------------------------------------------------
template<bool OUT_BF16>
__global__ __launch_bounds__(256)
void gemm_bt(const short* __restrict__ A, size_t sA, int lda,
             const short* __restrict__ Bm, size_t sB, int ldb,
             void* __restrict__ C, size_t sC, int ldc,
             const float* __restrict__ bias, int K, float scale)
{
    __shared__ short As[BM][BK];  // unpadded: global_load_lds layout constraint
    __shared__ short Bs[BN][BK];
    const int bz = blockIdx.z;
    const short* Ab = A  + (size_t)bz * sA;
    const short* Bb = Bm + (size_t)bz * sB;
    const int m0 = blockIdx.y * BM;
    const int n0 = blockIdx.x * BN;
    const int tid  = threadIdx.x;
    const int lane = tid & 63;
    const int wave = tid >> 6;
    const int wr = wave >> 1, wc = wave & 1;
    const int lr = lane & 15;
    const int lq = lane >> 4;

    floatx4 acc[4][4];
    #pragma unroll
    for (int i = 0; i < 4; ++i)
        #pragma unroll
        for (int j = 0; j < 4; ++j) acc[i][j] = (floatx4)(0.f);

    for (int k0 = 0; k0 < K; k0 += BK) {
        __syncthreads();
        #pragma unroll
        for (int h = 0; h < 2; ++h) {
            const int c   = tid + h * 256;
            const int row = c >> 2;
            const int kc  = (c & 3) * 8;   // LDS byte addr = c*16 = wavebase + lane*16
            async16(Ab + (size_t)(m0 + row) * lda + k0 + kc, &As[row][kc]);
            async16(Bb + (size_t)(n0 + row) * ldb + k0 + kc, &Bs[row][kc]);
        }
        __syncthreads();
        bf16x8 af[4], bfr[4];
        #pragma unroll
        for (int i = 0; i < 4; ++i)
            af[i] = *(const bf16x8*)&As[wr * 64 + i * 16 + lr][lq * 8];
        #pragma unroll
        for (int j = 0; j < 4; ++j)
            bfr[j] = *(const bf16x8*)&Bs[wc * 64 + j * 16 + lr][lq * 8];
        #pragma unroll
        for (int i = 0; i < 4; ++i)
            #pragma unroll
            for (int j = 0; j < 4; ++j)
                acc[i][j] = __builtin_amdgcn_mfma_f32_16x16x32_bf16(
                    af[i], bfr[j], acc[i][j], 0, 0, 0);
    }

    // D layout: col = lane&15, row = (lane>>4)*4 + r  [m89-verified]
    #pragma unroll
    for (int j = 0; j < 4; ++j) {
        const int gn = n0 + wc * 64 + j * 16 + lr;
        const float bv = bias ? bias[gn] : 0.f;
        #pragma unroll
        for (int i = 0; i < 4; ++i) {
            #pragma unroll
            for (int r = 0; r < 4; ++r) {
                const int gm = m0 + wr * 64 + i * 16 + lq * 4 + r;
                const float v = acc[i][j][r] * scale + bv;
                if (OUT_BF16) {
                    ((short*)C)[(size_t)bz * sC + (size_t)gm * ldc + gn] = f2bf(v);
                } else {
                    ((float*)C)[(size_t)bz * sC + (size_t)gm * ldc + gn] = v;
                }
            }
        }
    }
}

// ---------------------------------------------------------------------------
// Row softmax, in place on bf16 [M1 rows][SEQ]. fp32 math.
// ---------------------------------------------------------------------------
__global__ __launch_bounds__(256)
void softmax_kernel(short* __restrict__ P)
{
    const int row  = blockIdx.x;
    short* p = P + (size_t)row * SEQ;
    const int t    = threadIdx.x;
    const int lane = t & 63;
    const int wave = t >> 6;
    __shared__ float red[8];

    bf16x8 raw = *(const bf16x8*)(p + t * 8);
    float v[8];
    float mx = -1e30f;
    #pragma unroll
    for (int j = 0; j < 8; ++j) { v[j] = bf2f(raw[j]); mx = fmaxf(mx, v[j]); }
    #pragma unroll
    for (int off = 32; off > 0; off >>= 1) mx = fmaxf(mx, __shfl_xor(mx, off));
    if (lane == 0) red[wave] = mx;
    __syncthreads();
    mx = fmaxf(fmaxf(red[0], red[1]), fmaxf(red[2], red[3]));

    float e[8], s = 0.f;
    #pragma unroll
    for (int j = 0; j < 8; ++j) { e[j] = __expf(v[j] - mx); s += e[j]; }
    #pragma unroll
    for (int off = 32; off > 0; off >>= 1) s += __shfl_xor(s, off);
    if (lane == 0) red[4 + wave] = s;
    __syncthreads();
    s = red[4] + red[5] + red[6] + red[7];
    const float inv = 1.f / s;

    bf16x8 o;
    #pragma unroll
    for (int j = 0; j < 8; ++j) o[j] = f2bf(e[j] * inv);
    *(bf16x8*)(p + t * 8) = o;
}

// ---------------------------------------------------------------------------
extern "C" void kernel_launch(void* const* d_in, const int* in_sizes, int n_in,
                              void* d_out, int out_size, void* d_ws, size_t ws_size,
                              hipStream_t stream)
{
    const float* query = (const float*)d_in[0];
    const float* key_  = (const float*)d_in[1];
    const float* value = (const float*)d_in[2];
    const float* ctx   = (const float*)d_in[3];
    const float* Wq    = (const float*)d_in[4];
    const float* bq    = (const float*)d_in[5];
    const float* Wk    = (const float*)d_in[6];
    const float* bk    = (const float*)d_in[7];
    const float* Wv    = (const float*)d_in[8];
    const float* bv    = (const float*)d_in[9];

    // Workspace choreography (peak 80 MB):
    //   [ 0,16)  slotX: bf16 staging for v/q/k input (sequential reuse)
    //   [16,22)  Wq_b, Wk_b, Wv_b (bf16) ; [22,+12K) effective biases (fp32)
    //   [ 0,32)  S_b  (written at scores time — slotX/weights/biases dead)
    //   [32,48)  v_p, then q_b
    //   [48,64)  v_t
    //   [64,80)  k_b
    char* ws = (char*)d_ws;
    const size_t MB = 1ull << 20;
    short* slotX = (short*)(ws);
    short* Wq_b  = (short*)(ws + 16 * MB);
    short* Wk_b  = (short*)(ws + 18 * MB);
    short* Wv_b  = (short*)(ws + 20 * MB);
    float* bq_e  = (float*)(ws + 22 * MB);
    float* bk_e  = (float*)(ws + 22 * MB + 4096);
    float* bv_e  = (float*)(ws + 22 * MB + 8192);
    short* S_b   = (short*)(ws);
    short* qb_vp = (short*)(ws + 32 * MB);
    short* v_t   = (short*)(ws + 48 * MB);
    short* k_b   = (short*)(ws + 64 * MB);

    dim3 blk(256);
    const int W8 = DIMN * DIMN / 8;  // 128K
    const int X8 = M1 * DIMN / 8;    // 1M

    // weights -> bf16, effective biases (ctx folded: (x+c)@W^T+b = x@W^T + (b + c@W^T))
    cvt_bf16<<<dim3((W8 + 255) / 256), blk, 0, stream>>>(Wq, Wq_b, W8);
    cvt_bf16<<<dim3((W8 + 255) / 256), blk, 0, stream>>>(Wk, Wk_b, W8);
    cvt_bf16<<<dim3((W8 + 255) / 256), blk, 0, stream>>>(Wv, Wv_b, W8);
    bias_ctx<<<dim3(DIMN / 4), blk, 0, stream>>>(Wq, bq, ctx, bq_e);
    bias_ctx<<<dim3(DIMN / 4), blk, 0, stream>>>(Wk, bk, ctx, bk_e);
    bias_ctx<<<dim3(DIMN / 4), blk, 0, stream>>>(Wv, bv, nullptr, bv_e);

    // V chain: cvt -> proj -> transpose
    cvt_bf16<<<dim3(X8 / 256), blk, 0, stream>>>(value, slotX, X8);
    gemm_bt<true><<<dim3(DIMN / BN, M1 / BM, 1), blk, 0, stream>>>(
        slotX, 0, DIMN, Wv_b, 0, DIMN, qb_vp, 0, DIMN, bv_e, DIMN, 1.f);
    transpose_v<<<dim3(DIMN / 64, SEQ / 64, BATCH), blk, 0, stream>>>(qb_vp, v_t);

    // Q chain
    cvt_bf16<<<dim3(X8 / 256), blk, 0, stream>>>(query, slotX, X8);
    gemm_bt<true><<<dim3(DIMN / BN, M1 / BM, 1), blk, 0, stream>>>(
        slotX, 0, DIMN, Wq_b, 0, DIMN, qb_vp, 0, DIMN, bq_e, DIMN, 1.f);

    // K chain
    cvt_bf16<<<dim3(X8 / 256), blk, 0, stream>>>(key_, slotX, X8);
    gemm_bt<true><<<dim3(DIMN / BN, M1 / BM, 1), blk, 0, stream>>>(
        slotX, 0, DIMN, Wk_b, 0, DIMN, k_b, 0, DIMN, bk_e, DIMN, 1.f);

    // scores = q @ k^T * scale   [B][S][S] bf16
    const float scale = 1.0f / 32.0f; // DIMN^-0.5
    gemm_bt<true><<<dim3(SEQ / BN, SEQ / BM, BATCH), blk, 0, stream>>>(
        qb_vp, (size_t)SEQ * DIMN, DIMN,
        k_b,   (size_t)SEQ * DIMN, DIMN,
        S_b,   (size_t)SEQ * SEQ,  SEQ, nullptr, DIMN, scale);

    softmax_kernel<<<dim3(M1), blk, 0, stream>>>(S_b);

    // out = P @ V  (= P @ (v_t)^T), fp32 out
    gemm_bt<false><<<dim3(DIMN / BN, SEQ / BM, BATCH), blk, 0, stream>>>(
        S_b, (size_t)SEQ * SEQ,  SEQ,
        v_t, (size_t)DIMN * SEQ, SEQ,
        d_out, (size_t)SEQ * DIMN, DIMN, nullptr, SEQ, 1.f);
}

// Round 3
// 395.252 us; speedup vs baseline: 1.0661x; 1.0517x over previous
//
#include <hip/hip_runtime.h>

typedef __attribute__((ext_vector_type(8))) short bf16x8;
typedef __attribute__((ext_vector_type(4))) float floatx4;

constexpr int BATCH = 4;
constexpr int SEQ   = 2048;
constexpr int DIMN  = 1024;
constexpr int M1    = BATCH * SEQ; // 8192

constexpr int BM = 128, BN = 128, BK = 32;

__device__ __forceinline__ short f2bf(float f) {
    union { float f; unsigned u; } x; x.f = f;
    unsigned r = x.u + 0x7fffu + ((x.u >> 16) & 1u); // RNE
    return (short)(r >> 16);
}
__device__ __forceinline__ float bf2f(short s) {
    union { unsigned u; float f; } x; x.u = ((unsigned)(unsigned short)s) << 16;
    return x.f;
}

__device__ __forceinline__ void async16(const void* g, void* l) {
    __builtin_amdgcn_global_load_lds(
        (const __attribute__((address_space(1))) unsigned int*)g,
        (__attribute__((address_space(3))) unsigned int*)l, 16, 0, 0);
}

// ---------------------------------------------------------------------------
// GEMM core: C = A @ B^T (*scale + bias), bf16 in, 128x128x32 tiles,
// async double-buffered single-barrier K-loop:
//   stage(k+1 -> buf^1); compute(buf); barrier   — the vmcnt(0) drain the
// compiler emits before s_barrier lands AFTER the MFMA work, hiding load
// latency; one barrier per iter instead of two.
// ---------------------------------------------------------------------------
template<bool OUT_BF16>
__device__ __forceinline__ void gemm_core(
    const short* __restrict__ Ab, int lda,
    const short* __restrict__ Bb, int ldb,
    void* __restrict__ Cb, int ldc,
    const float* __restrict__ bias, int K, float scale,
    int m0, int n0)
{
    __shared__ short As[2][BM][BK];   // unpadded: global_load_lds layout
    __shared__ short Bs[2][BN][BK];

    const int tid  = threadIdx.x;
    const int lane = tid & 63;
    const int wave = tid >> 6;
    const int wr = wave >> 1, wc = wave & 1;
    const int lr = lane & 15;
    const int lq = lane >> 4;

    floatx4 acc[4][4];
    #pragma unroll
    for (int i = 0; i < 4; ++i)
        #pragma unroll
        for (int j = 0; j < 4; ++j) acc[i][j] = (floatx4)(0.f);

    auto stage = [&](int k0, int bi) {
        #pragma unroll
        for (int h = 0; h < 2; ++h) {
            const int c   = tid + h * 256;
            const int row = c >> 2;
            const int kc  = (c & 3) * 8;  // LDS byte addr = c*16 = wavebase + lane*16
            async16(Ab + (size_t)(m0 + row) * lda + k0 + kc, &As[bi][row][kc]);
            async16(Bb + (size_t)(n0 + row) * ldb + k0 + kc, &Bs[bi][row][kc]);
        }
    };

    const int NK = K / BK;
    stage(0, 0);
    __syncthreads();

    for (int it = 0; it < NK; ++it) {
        const int bi = it & 1;
        if (it + 1 < NK) stage((it + 1) * BK, bi ^ 1);  // async prefetch

        bf16x8 af[4], bfr[4];
        #pragma unroll
        for (int i = 0; i < 4; ++i)
            af[i] = *(const bf16x8*)&As[bi][wr * 64 + i * 16 + lr][lq * 8];
        #pragma unroll
        for (int j = 0; j < 4; ++j)
            bfr[j] = *(const bf16x8*)&Bs[bi][wc * 64 + j * 16 + lr][lq * 8];
        #pragma unroll
        for (int i = 0; i < 4; ++i)
            #pragma unroll
            for (int j = 0; j < 4; ++j)
                acc[i][j] = __builtin_amdgcn_mfma_f32_16x16x32_bf16(
                    af[i], bfr[j], acc[i][j], 0, 0, 0);

        if (it + 1 < NK) __syncthreads();  // drains prefetch; protects buf reuse
    }

    // D layout: col = lane&15, row = (lane>>4)*4 + r  [m89-verified]
    #pragma unroll
    for (int j = 0; j < 4; ++j) {
        const int gn = n0 + wc * 64 + j * 16 + lr;
        const float bv = bias ? bias[gn] : 0.f;
        #pragma unroll
        for (int i = 0; i < 4; ++i) {
            #pragma unroll
            for (int r = 0; r < 4; ++r) {
                const int gm = m0 + wr * 64 + i * 16 + lq * 4 + r;
                const float v = acc[i][j][r] * scale + bv;
                if (OUT_BF16) {
                    ((short*)Cb)[(size_t)gm * ldc + gn] = f2bf(v);
                } else {
                    ((float*)Cb)[(size_t)gm * ldc + gn] = v;
                }
            }
        }
    }
}

// ---------------------------------------------------------------------------
__global__ __launch_bounds__(256)
void proj_qk(const short* __restrict__ xq, const short* __restrict__ xk,
             const short* __restrict__ Wq_, const short* __restrict__ Wk_,
             const float* __restrict__ bq_, const float* __restrict__ bk_,
             short* __restrict__ q, short* __restrict__ k)
{
    const int z = blockIdx.z;
    gemm_core<true>(z ? xk : xq, DIMN, z ? Wk_ : Wq_, DIMN,
                    z ? (void*)k : (void*)q, DIMN,
                    z ? bk_ : bq_, DIMN, 1.f,
                    blockIdx.y * BM, blockIdx.x * BN);
}

__global__ __launch_bounds__(256)
void proj_v(const short* __restrict__ xv, const short* __restrict__ Wv_,
            const float* __restrict__ bv_, short* __restrict__ vp)
{
    gemm_core<true>(xv, DIMN, Wv_, DIMN, (void*)vp, DIMN, bv_, DIMN, 1.f,
                    blockIdx.y * BM, blockIdx.x * BN);
}

template<bool OUT_BF16>
__global__ __launch_bounds__(256)
void gemm_batched(const short* __restrict__ A, size_t sA, int lda,
                  const short* __restrict__ Bm, size_t sB, int ldb,
                  void* __restrict__ C, size_t sC, int ldc,
                  int K, float scale)
{
    const int bz = blockIdx.z;
    char* Cb = (char*)C + (size_t)bz * sC * (OUT_BF16 ? 2 : 4);
    gemm_core<OUT_BF16>(A + (size_t)bz * sA, lda, Bm + (size_t)bz * sB, ldb,
                        (void*)Cb, ldc, nullptr, K, scale,
                        blockIdx.y * BM, blockIdx.x * BN);
}

// ---------------------------------------------------------------------------
// fp32 -> bf16 bulk convert, up to 2 arrays per launch (blockIdx.z picks).
// ---------------------------------------------------------------------------
__global__ __launch_bounds__(256)
void cvt_dual(const float* __restrict__ in0, short* __restrict__ out0,
              const float* __restrict__ in1, short* __restrict__ out1, int n8)
{
    const float* in = blockIdx.z ? in1 : in0;
    short* out      = blockIdx.z ? out1 : out0;
    const int i = blockIdx.x * 256 + threadIdx.x;
    if (i >= n8) return;
    const float4 a0 = ((const float4*)in)[(size_t)i * 2];
    const float4 a1 = ((const float4*)in)[(size_t)i * 2 + 1];
    const float v[8] = {a0.x, a0.y, a0.z, a0.w, a1.x, a1.y, a1.z, a1.w};
    bf16x8 o;
    #pragma unroll
    for (int j = 0; j < 8; ++j) o[j] = f2bf(v[j]);
    *(bf16x8*)(out + (size_t)i * 8) = o;
}

// ---------------------------------------------------------------------------
// Effective biases: out[n] = b[n] + dot(ctx, W[n,:]) (ctx only for q,k).
// grid (DIMN/4, 3): y picks which projection.
// ---------------------------------------------------------------------------
__global__ __launch_bounds__(256)
void bias3(const float* __restrict__ Wq, const float* __restrict__ Wk,
           const float* __restrict__ Wv,
           const float* __restrict__ bq, const float* __restrict__ bk,
           const float* __restrict__ bv,
           const float* __restrict__ ctx,
           float* __restrict__ oq, float* __restrict__ ok, float* __restrict__ ov)
{
    const int z = blockIdx.y;
    const float* W = (z == 0) ? Wq : (z == 1) ? Wk : Wv;
    const float* b = (z == 0) ? bq : (z == 1) ? bk : bv;
    float*       o = (z == 0) ? oq : (z == 1) ? ok : ov;
    const int n    = blockIdx.x * 4 + (threadIdx.x >> 6);
    const int lane = threadIdx.x & 63;
    float s = 0.f;
    if (z < 2) {
        const float* row = W + (size_t)n * DIMN;
        for (int k = lane * 4; k < DIMN; k += 256) {
            const float4 x = *(const float4*)(row + k);
            const float4 c = *(const float4*)(ctx + k);
            s += x.x * c.x + x.y * c.y + x.z * c.z + x.w * c.w;
        }
        #pragma unroll
        for (int off = 32; off > 0; off >>= 1) s += __shfl_xor(s, off);
    }
    if (lane == 0) o[n] = b[n] + s;
}

// ---------------------------------------------------------------------------
// bf16 transpose: in [B][S][D] -> out [B][D][S], 64x64 LDS tiles.
// ---------------------------------------------------------------------------
__global__ __launch_bounds__(256)
void transpose_v(const short* __restrict__ in, short* __restrict__ out)
{
    __shared__ short t[64][68];
    const int b  = blockIdx.z;
    const int d0 = blockIdx.x * 64;
    const int s0 = blockIdx.y * 64;
    const int r  = threadIdx.x >> 3;
    const int c  = (threadIdx.x & 7) * 8;
    #pragma unroll
    for (int h = 0; h < 2; ++h) {
        const int s = r + h * 32;
        bf16x8 v = *(const bf16x8*)(in + ((size_t)b * SEQ + s0 + s) * DIMN + d0 + c);
        #pragma unroll
        for (int j = 0; j < 8; ++j) t[c + j][s] = v[j];
    }
    __syncthreads();
    #pragma unroll
    for (int h = 0; h < 2; ++h) {
        const int d = r + h * 32;
        bf16x8 v;
        #pragma unroll
        for (int j = 0; j < 8; ++j) v[j] = t[d][c + j];
        *(bf16x8*)(out + ((size_t)b * DIMN + d0 + d) * SEQ + s0 + c) = v;
    }
}

// ---------------------------------------------------------------------------
// Row softmax, in place on bf16 [M1 rows][SEQ]. fp32 math.
// ---------------------------------------------------------------------------
__global__ __launch_bounds__(256)
void softmax_kernel(short* __restrict__ P)
{
    const int row  = blockIdx.x;
    short* p = P + (size_t)row * SEQ;
    const int t    = threadIdx.x;
    const int lane = t & 63;
    const int wave = t >> 6;
    __shared__ float red[8];

    bf16x8 raw = *(const bf16x8*)(p + t * 8);
    float v[8];
    float mx = -1e30f;
    #pragma unroll
    for (int j = 0; j < 8; ++j) { v[j] = bf2f(raw[j]); mx = fmaxf(mx, v[j]); }
    #pragma unroll
    for (int off = 32; off > 0; off >>= 1) mx = fmaxf(mx, __shfl_xor(mx, off));
    if (lane == 0) red[wave] = mx;
    __syncthreads();
    mx = fmaxf(fmaxf(red[0], red[1]), fmaxf(red[2], red[3]));

    float e[8], s = 0.f;
    #pragma unroll
    for (int j = 0; j < 8; ++j) { e[j] = __expf(v[j] - mx); s += e[j]; }
    #pragma unroll
    for (int off = 32; off > 0; off >>= 1) s += __shfl_xor(s, off);
    if (lane == 0) red[4 + wave] = s;
    __syncthreads();
    s = red[4] + red[5] + red[6] + red[7];
    const float inv = 1.f / s;

    bf16x8 o;
    #pragma unroll
    for (int j = 0; j < 8; ++j) o[j] = f2bf(e[j] * inv);
    *(bf16x8*)(p + t * 8) = o;
}

// ---------------------------------------------------------------------------
extern "C" void kernel_launch(void* const* d_in, const int* in_sizes, int n_in,
                              void* d_out, int out_size, void* d_ws, size_t ws_size,
                              hipStream_t stream)
{
    const float* query = (const float*)d_in[0];
    const float* key_  = (const float*)d_in[1];
    const float* value = (const float*)d_in[2];
    const float* ctx   = (const float*)d_in[3];
    const float* Wq    = (const float*)d_in[4];
    const float* bq    = (const float*)d_in[5];
    const float* Wk    = (const float*)d_in[6];
    const float* bk    = (const float*)d_in[7];
    const float* Wv    = (const float*)d_in[8];
    const float* bv    = (const float*)d_in[9];

    // Workspace lifetimes (MB), peak 80:
    //   xq [0,16) xk [16,32)  -> after proj_qk: xv [0,16), vp [16,32)
    //   -> after transpose:    S_b [0,32)
    //   q_b [32,48), k_b [48,64)                        (live until scores)
    //   W3 [64,70) + biases [70,+12KB)  -> after proj_v: v_t [64,80)
    char* ws = (char*)d_ws;
    const size_t MB = 1ull << 20;
    short* xq   = (short*)(ws);
    short* xk   = (short*)(ws + 16 * MB);
    short* q_b  = (short*)(ws + 32 * MB);
    short* k_b  = (short*)(ws + 48 * MB);
    short* Wq_b = (short*)(ws + 64 * MB);
    short* Wk_b = (short*)(ws + 66 * MB);
    short* Wv_b = (short*)(ws + 68 * MB);
    float* bq_e = (float*)(ws + 70 * MB);
    float* bk_e = (float*)(ws + 70 * MB + 4096);
    float* bv_e = (float*)(ws + 70 * MB + 8192);
    short* xv   = (short*)(ws);
    short* vp   = (short*)(ws + 16 * MB);
    short* S_b  = (short*)(ws);
    short* v_t  = (short*)(ws + 64 * MB);

    dim3 blk(256);
    const int W8 = DIMN * DIMN / 8;  // 131072
    const int X8 = M1 * DIMN / 8;    // 1048576

    cvt_dual<<<dim3(W8 / 256, 1, 2), blk, 0, stream>>>(Wq, Wq_b, Wk, Wk_b, W8);
    cvt_dual<<<dim3(W8 / 256, 1, 1), blk, 0, stream>>>(Wv, Wv_b, nullptr, nullptr, W8);
    bias3<<<dim3(DIMN / 4, 3), blk, 0, stream>>>(Wq, Wk, Wv, bq, bk, bv, ctx,
                                                 bq_e, bk_e, bv_e);

    cvt_dual<<<dim3(X8 / 256, 1, 2), blk, 0, stream>>>(query, xq, key_, xk, X8);
    proj_qk<<<dim3(DIMN / BN, M1 / BM, 2), blk, 0, stream>>>(
        xq, xk, Wq_b, Wk_b, bq_e, bk_e, q_b, k_b);

    cvt_dual<<<dim3(X8 / 256, 1, 1), blk, 0, stream>>>(value, xv, nullptr, nullptr, X8);
    proj_v<<<dim3(DIMN / BN, M1 / BM, 1), blk, 0, stream>>>(xv, Wv_b, bv_e, vp);
    transpose_v<<<dim3(DIMN / 64, SEQ / 64, BATCH), blk, 0, stream>>>(vp, v_t);

    const float scale = 1.0f / 32.0f; // DIMN^-0.5
    gemm_batched<true><<<dim3(SEQ / BN, SEQ / BM, BATCH), blk, 0, stream>>>(
        q_b, (size_t)SEQ * DIMN, DIMN,
        k_b, (size_t)SEQ * DIMN, DIMN,
        S_b, (size_t)SEQ * SEQ,  SEQ, DIMN, scale);

    softmax_kernel<<<dim3(M1), blk, 0, stream>>>(S_b);

    gemm_batched<false><<<dim3(DIMN / BN, SEQ / BM, BATCH), blk, 0, stream>>>(
        S_b, (size_t)SEQ * SEQ,  SEQ,
        v_t, (size_t)DIMN * SEQ, SEQ,
        d_out, (size_t)SEQ * DIMN, DIMN, SEQ, 1.f);
}

// Round 4
// 374.148 us; speedup vs baseline: 1.1262x; 1.0564x over previous
//
#include <hip/hip_runtime.h>

typedef __attribute__((ext_vector_type(8))) short bf16x8;
typedef __attribute__((ext_vector_type(4))) float floatx4;

constexpr int BATCH = 4;
constexpr int SEQ   = 2048;
constexpr int DIMN  = 1024;
constexpr int M1    = BATCH * SEQ; // 8192

constexpr int BM = 128, BN = 128, BK = 32;

__device__ __forceinline__ short f2bf(float f) {
    union { float f; unsigned u; } x; x.f = f;
    unsigned r = x.u + 0x7fffu + ((x.u >> 16) & 1u); // RNE
    return (short)(r >> 16);
}
__device__ __forceinline__ float bf2f(short s) {
    union { unsigned u; float f; } x; x.u = ((unsigned)(unsigned short)s) << 16;
    return x.f;
}

__device__ __forceinline__ void async16(const void* g, void* l) {
    __builtin_amdgcn_global_load_lds(
        (const __attribute__((address_space(1))) unsigned int*)g,
        (__attribute__((address_space(3))) unsigned int*)l, 16, 0, 0);
}

// ---------------------------------------------------------------------------
// GEMM core: C = A @ B^T (*scale + bias), bf16 in, 128x128x32 tiles,
// async double-buffered single-barrier K-loop (R3-verified).
// ---------------------------------------------------------------------------
template<bool OUT_BF16>
__device__ __forceinline__ void gemm_core(
    const short* __restrict__ Ab, int lda,
    const short* __restrict__ Bb, int ldb,
    void* __restrict__ Cb, int ldc,
    const float* __restrict__ bias, int K, float scale,
    int m0, int n0)
{
    __shared__ short As[2][BM][BK];   // unpadded: global_load_lds layout
    __shared__ short Bs[2][BN][BK];

    const int tid  = threadIdx.x;
    const int lane = tid & 63;
    const int wave = tid >> 6;
    const int wr = wave >> 1, wc = wave & 1;
    const int lr = lane & 15;
    const int lq = lane >> 4;

    floatx4 acc[4][4];
    #pragma unroll
    for (int i = 0; i < 4; ++i)
        #pragma unroll
        for (int j = 0; j < 4; ++j) acc[i][j] = (floatx4)(0.f);

    auto stage = [&](int k0, int bi) {
        #pragma unroll
        for (int h = 0; h < 2; ++h) {
            const int c   = tid + h * 256;
            const int row = c >> 2;
            const int kc  = (c & 3) * 8;  // LDS byte addr = c*16 = wavebase + lane*16
            async16(Ab + (size_t)(m0 + row) * lda + k0 + kc, &As[bi][row][kc]);
            async16(Bb + (size_t)(n0 + row) * ldb + k0 + kc, &Bs[bi][row][kc]);
        }
    };

    const int NK = K / BK;
    stage(0, 0);
    __syncthreads();

    for (int it = 0; it < NK; ++it) {
        const int bi = it & 1;
        if (it + 1 < NK) stage((it + 1) * BK, bi ^ 1);  // async prefetch

        bf16x8 af[4], bfr[4];
        #pragma unroll
        for (int i = 0; i < 4; ++i)
            af[i] = *(const bf16x8*)&As[bi][wr * 64 + i * 16 + lr][lq * 8];
        #pragma unroll
        for (int j = 0; j < 4; ++j)
            bfr[j] = *(const bf16x8*)&Bs[bi][wc * 64 + j * 16 + lr][lq * 8];
        #pragma unroll
        for (int i = 0; i < 4; ++i)
            #pragma unroll
            for (int j = 0; j < 4; ++j)
                acc[i][j] = __builtin_amdgcn_mfma_f32_16x16x32_bf16(
                    af[i], bfr[j], acc[i][j], 0, 0, 0);

        if (it + 1 < NK) __syncthreads();
    }

    // D layout: col = lane&15, row = (lane>>4)*4 + r  [m89-verified]
    #pragma unroll
    for (int j = 0; j < 4; ++j) {
        const int gn = n0 + wc * 64 + j * 16 + lr;
        const float bv = bias ? bias[gn] : 0.f;
        #pragma unroll
        for (int i = 0; i < 4; ++i) {
            #pragma unroll
            for (int r = 0; r < 4; ++r) {
                const int gm = m0 + wr * 64 + i * 16 + lq * 4 + r;
                const float v = acc[i][j][r] * scale + bv;
                if (OUT_BF16) {
                    ((short*)Cb)[(size_t)gm * ldc + gn] = f2bf(v);
                } else {
                    ((float*)Cb)[(size_t)gm * ldc + gn] = v;
                }
            }
        }
    }
}

// ---------------------------------------------------------------------------
// XCD-swizzled wrappers. xcd = blockIdx.x & 7 (MI355X round-robin heuristic);
// each XCD owns a contiguous group of m-panels so co-resident blocks share
// A-panels in their private L2 (4 MiB/XCD).
// ---------------------------------------------------------------------------
// q/k projection: 1024 blocks. XCD x -> m-panels [8x, 8x+8), z in {q,k}, n all 8.
__global__ __launch_bounds__(256)
void proj_qk(const short* __restrict__ xq, const short* __restrict__ xk,
             const short* __restrict__ Wq_, const short* __restrict__ Wk_,
             const float* __restrict__ bq_, const float* __restrict__ bk_,
             short* __restrict__ q, short* __restrict__ k)
{
    const int b   = blockIdx.x;
    const int xcd = b & 7;
    const int i   = b >> 3;          // 0..127
    const int z   = i >> 6;          // 0..1
    const int mm  = (i >> 3) & 7;
    const int nn  = i & 7;
    gemm_core<true>(z ? xk : xq, DIMN, z ? Wk_ : Wq_, DIMN,
                    z ? (void*)k : (void*)q, DIMN,
                    z ? bk_ : bq_, DIMN, 1.f,
                    (xcd * 8 + mm) * BM, nn * BN);
}

// v projection: 512 blocks. XCD x -> m-panels [8x, 8x+8), n all 8.
__global__ __launch_bounds__(256)
void proj_v(const short* __restrict__ xv, const short* __restrict__ Wv_,
            const float* __restrict__ bv_, short* __restrict__ vp)
{
    const int b   = blockIdx.x;
    const int xcd = b & 7;
    const int i   = b >> 3;          // 0..63
    const int mm  = i >> 3;
    const int nn  = i & 7;
    gemm_core<true>(xv, DIMN, Wv_, DIMN, (void*)vp, DIMN, bv_, DIMN, 1.f,
                    (xcd * 8 + mm) * BM, nn * BN);
}

// scores: 1024 blocks. XCD x -> batch x>>1, m-panels [(x&1)*8, +8), n all 16.
__global__ __launch_bounds__(256)
void gemm_scores(const short* __restrict__ q, const short* __restrict__ k,
                 short* __restrict__ S, float scale)
{
    const int b   = blockIdx.x;
    const int xcd = b & 7;
    const int i   = b >> 3;          // 0..127
    const int bz  = xcd >> 1;
    const int mh  = xcd & 1;
    const int mm  = i >> 4;          // 0..7
    const int nn  = i & 15;          // 0..15
    gemm_core<true>(q + (size_t)bz * SEQ * DIMN, DIMN,
                    k + (size_t)bz * SEQ * DIMN, DIMN,
                    (void*)(S + (size_t)bz * SEQ * SEQ), SEQ,
                    nullptr, DIMN, scale,
                    (mh * 8 + mm) * BM, nn * BN);
}

// PV: 512 blocks. XCD x -> batch x>>1, m-panels [(x&1)*8, +8), n all 8.
__global__ __launch_bounds__(256)
void gemm_pv(const short* __restrict__ P, const short* __restrict__ vt,
             float* __restrict__ O)
{
    const int b   = blockIdx.x;
    const int xcd = b & 7;
    const int i   = b >> 3;          // 0..63
    const int bz  = xcd >> 1;
    const int mh  = xcd & 1;
    const int mm  = i >> 3;          // 0..7
    const int nn  = i & 7;           // 0..7
    gemm_core<false>(P  + (size_t)bz * SEQ * SEQ,  SEQ,
                     vt + (size_t)bz * DIMN * SEQ, SEQ,
                     (void*)(O + (size_t)bz * SEQ * DIMN), DIMN,
                     nullptr, SEQ, 1.f,
                     (mh * 8 + mm) * BM, nn * BN);
}

// ---------------------------------------------------------------------------
// fp32 -> bf16 bulk convert, up to 3 arrays per launch (blockIdx.z picks).
// ---------------------------------------------------------------------------
__global__ __launch_bounds__(256)
void cvt_tri(const float* __restrict__ in0, short* __restrict__ out0,
             const float* __restrict__ in1, short* __restrict__ out1,
             const float* __restrict__ in2, short* __restrict__ out2, int n8)
{
    const int z = blockIdx.z;
    const float* in = (z == 0) ? in0 : (z == 1) ? in1 : in2;
    short* out      = (z == 0) ? out0 : (z == 1) ? out1 : out2;
    const int i = blockIdx.x * 256 + threadIdx.x;
    if (i >= n8) return;
    const float4 a0 = ((const float4*)in)[(size_t)i * 2];
    const float4 a1 = ((const float4*)in)[(size_t)i * 2 + 1];
    const float v[8] = {a0.x, a0.y, a0.z, a0.w, a1.x, a1.y, a1.z, a1.w};
    bf16x8 o;
    #pragma unroll
    for (int j = 0; j < 8; ++j) o[j] = f2bf(v[j]);
    *(bf16x8*)(out + (size_t)i * 8) = o;
}

// ---------------------------------------------------------------------------
// Effective biases: out[n] = b[n] + dot(ctx, W[n,:]) (ctx only for q,k).
// ---------------------------------------------------------------------------
__global__ __launch_bounds__(256)
void bias3(const float* __restrict__ Wq, const float* __restrict__ Wk,
           const float* __restrict__ Wv,
           const float* __restrict__ bq, const float* __restrict__ bk,
           const float* __restrict__ bv,
           const float* __restrict__ ctx,
           float* __restrict__ oq, float* __restrict__ ok, float* __restrict__ ov)
{
    const int z = blockIdx.y;
    const float* W = (z == 0) ? Wq : (z == 1) ? Wk : Wv;
    const float* b = (z == 0) ? bq : (z == 1) ? bk : bv;
    float*       o = (z == 0) ? oq : (z == 1) ? ok : ov;
    const int n    = blockIdx.x * 4 + (threadIdx.x >> 6);
    const int lane = threadIdx.x & 63;
    float s = 0.f;
    if (z < 2) {
        const float* row = W + (size_t)n * DIMN;
        for (int k = lane * 4; k < DIMN; k += 256) {
            const float4 x = *(const float4*)(row + k);
            const float4 c = *(const float4*)(ctx + k);
            s += x.x * c.x + x.y * c.y + x.z * c.z + x.w * c.w;
        }
        #pragma unroll
        for (int off = 32; off > 0; off >>= 1) s += __shfl_xor(s, off);
    }
    if (lane == 0) o[n] = b[n] + s;
}

// ---------------------------------------------------------------------------
// bf16 transpose: in [B][S][D] -> out [B][D][S], 64x64 LDS tiles.
// ---------------------------------------------------------------------------
__global__ __launch_bounds__(256)
void transpose_v(const short* __restrict__ in, short* __restrict__ out)
{
    __shared__ short t[64][68];
    const int b  = blockIdx.z;
    const int d0 = blockIdx.x * 64;
    const int s0 = blockIdx.y * 64;
    const int r  = threadIdx.x >> 3;
    const int c  = (threadIdx.x & 7) * 8;
    #pragma unroll
    for (int h = 0; h < 2; ++h) {
        const int s = r + h * 32;
        bf16x8 v = *(const bf16x8*)(in + ((size_t)b * SEQ + s0 + s) * DIMN + d0 + c);
        #pragma unroll
        for (int j = 0; j < 8; ++j) t[c + j][s] = v[j];
    }
    __syncthreads();
    #pragma unroll
    for (int h = 0; h < 2; ++h) {
        const int d = r + h * 32;
        bf16x8 v;
        #pragma unroll
        for (int j = 0; j < 8; ++j) v[j] = t[d][c + j];
        *(bf16x8*)(out + ((size_t)b * DIMN + d0 + d) * SEQ + s0 + c) = v;
    }
}

// ---------------------------------------------------------------------------
// Row softmax, in place on bf16 [M1 rows][SEQ]. fp32 math.
// ---------------------------------------------------------------------------
__global__ __launch_bounds__(256)
void softmax_kernel(short* __restrict__ P)
{
    const int row  = blockIdx.x;
    short* p = P + (size_t)row * SEQ;
    const int t    = threadIdx.x;
    const int lane = t & 63;
    const int wave = t >> 6;
    __shared__ float red[8];

    bf16x8 raw = *(const bf16x8*)(p + t * 8);
    float v[8];
    float mx = -1e30f;
    #pragma unroll
    for (int j = 0; j < 8; ++j) { v[j] = bf2f(raw[j]); mx = fmaxf(mx, v[j]); }
    #pragma unroll
    for (int off = 32; off > 0; off >>= 1) mx = fmaxf(mx, __shfl_xor(mx, off));
    if (lane == 0) red[wave] = mx;
    __syncthreads();
    mx = fmaxf(fmaxf(red[0], red[1]), fmaxf(red[2], red[3]));

    float e[8], s = 0.f;
    #pragma unroll
    for (int j = 0; j < 8; ++j) { e[j] = __expf(v[j] - mx); s += e[j]; }
    #pragma unroll
    for (int off = 32; off > 0; off >>= 1) s += __shfl_xor(s, off);
    if (lane == 0) red[4 + wave] = s;
    __syncthreads();
    s = red[4] + red[5] + red[6] + red[7];
    const float inv = 1.f / s;

    bf16x8 o;
    #pragma unroll
    for (int j = 0; j < 8; ++j) o[j] = f2bf(e[j] * inv);
    *(bf16x8*)(p + t * 8) = o;
}

// ---------------------------------------------------------------------------
extern "C" void kernel_launch(void* const* d_in, const int* in_sizes, int n_in,
                              void* d_out, int out_size, void* d_ws, size_t ws_size,
                              hipStream_t stream)
{
    const float* query = (const float*)d_in[0];
    const float* key_  = (const float*)d_in[1];
    const float* value = (const float*)d_in[2];
    const float* ctx   = (const float*)d_in[3];
    const float* Wq    = (const float*)d_in[4];
    const float* bq    = (const float*)d_in[5];
    const float* Wk    = (const float*)d_in[6];
    const float* bk    = (const float*)d_in[7];
    const float* Wv    = (const float*)d_in[8];
    const float* bv    = (const float*)d_in[9];

    // Workspace lifetimes (MB), peak 80:
    //   xq [0,16) xk [16,32)  -> after proj_qk: xv [0,16), vp [16,32)
    //   -> after transpose:    S_b [0,32)
    //   q_b [32,48), k_b [48,64)                        (live until scores)
    //   W3 [64,70) + biases [70,+12KB)  -> after proj_v: v_t [64,80)
    char* ws = (char*)d_ws;
    const size_t MB = 1ull << 20;
    short* xq   = (short*)(ws);
    short* xk   = (short*)(ws + 16 * MB);
    short* q_b  = (short*)(ws + 32 * MB);
    short* k_b  = (short*)(ws + 48 * MB);
    short* Wq_b = (short*)(ws + 64 * MB);
    short* Wk_b = (short*)(ws + 66 * MB);
    short* Wv_b = (short*)(ws + 68 * MB);
    float* bq_e = (float*)(ws + 70 * MB);
    float* bk_e = (float*)(ws + 70 * MB + 4096);
    float* bv_e = (float*)(ws + 70 * MB + 8192);
    short* xv   = (short*)(ws);
    short* vp   = (short*)(ws + 16 * MB);
    short* S_b  = (short*)(ws);
    short* v_t  = (short*)(ws + 64 * MB);

    dim3 blk(256);
    const int W8 = DIMN * DIMN / 8;  // 131072
    const int X8 = M1 * DIMN / 8;    // 1048576

    cvt_tri<<<dim3(W8 / 256, 1, 3), blk, 0, stream>>>(Wq, Wq_b, Wk, Wk_b, Wv, Wv_b, W8);
    bias3<<<dim3(DIMN / 4, 3), blk, 0, stream>>>(Wq, Wk, Wv, bq, bk, bv, ctx,
                                                 bq_e, bk_e, bv_e);

    cvt_tri<<<dim3(X8 / 256, 1, 2), blk, 0, stream>>>(query, xq, key_, xk,
                                                      nullptr, nullptr, X8);
    proj_qk<<<dim3(1024), blk, 0, stream>>>(xq, xk, Wq_b, Wk_b, bq_e, bk_e, q_b, k_b);

    cvt_tri<<<dim3(X8 / 256, 1, 1), blk, 0, stream>>>(value, xv, nullptr, nullptr,
                                                      nullptr, nullptr, X8);
    proj_v<<<dim3(512), blk, 0, stream>>>(xv, Wv_b, bv_e, vp);
    transpose_v<<<dim3(DIMN / 64, SEQ / 64, BATCH), blk, 0, stream>>>(vp, v_t);

    const float scale = 1.0f / 32.0f; // DIMN^-0.5
    gemm_scores<<<dim3(1024), blk, 0, stream>>>(q_b, k_b, S_b, scale);

    softmax_kernel<<<dim3(M1), blk, 0, stream>>>(S_b);

    gemm_pv<<<dim3(512), blk, 0, stream>>>(S_b, v_t, (float*)d_out);
}

// Round 5
// 348.107 us; speedup vs baseline: 1.2104x; 1.0748x over previous
//
#include <hip/hip_runtime.h>

typedef __attribute__((ext_vector_type(8))) short bf16x8;
typedef __attribute__((ext_vector_type(4))) float floatx4;

constexpr int BATCH = 4;
constexpr int SEQ   = 2048;
constexpr int DIMN  = 1024;
constexpr int M1    = BATCH * SEQ; // 8192

constexpr int BM = 128, BK = 32;

__device__ __forceinline__ short f2bf(float f) {
    union { float f; unsigned u; } x; x.f = f;
    unsigned r = x.u + 0x7fffu + ((x.u >> 16) & 1u); // RNE
    return (short)(r >> 16);
}
__device__ __forceinline__ float bf2f(short s) {
    union { unsigned u; float f; } x; x.u = ((unsigned)(unsigned short)s) << 16;
    return x.f;
}

__device__ __forceinline__ void async16(const void* g, void* l) {
    __builtin_amdgcn_global_load_lds(
        (const __attribute__((address_space(1))) unsigned int*)g,
        (__attribute__((address_space(3))) unsigned int*)l, 16, 0, 0);
}

// ---------------------------------------------------------------------------
// GEMM core: C = A @ B^T (*scale + bias), bf16 in, BM x (WJ*32) x BK tiles,
// async double-buffered single-barrier K-loop, pointer-increment staging.
// WJ=4: 128x128 tile (4 waves, 64x64 each). WJ=2: 128x64 (4 waves, 64x32).
// ---------------------------------------------------------------------------
template<bool OUT_BF16, int WJ>
__device__ __forceinline__ void gemm_core(
    const short* __restrict__ Ab, int lda,
    const short* __restrict__ Bb, int ldb,
    void* __restrict__ Cb, int ldc,
    const float* __restrict__ bias, int K, float scale,
    int m0, int n0)
{
    constexpr int BN_ = WJ * 32;
    __shared__ short As[2][BM][BK];    // unpadded: global_load_lds layout
    __shared__ short Bs[2][BN_][BK];

    const int tid  = threadIdx.x;
    const int lane = tid & 63;
    const int wave = tid >> 6;
    const int wr = wave >> 1, wc = wave & 1;
    const int lr = lane & 15;
    const int lq = lane >> 4;

    // staging map: each thread owns (row, kc) and row+64
    const int row = tid >> 2;            // 0..63
    const int kc  = (tid & 3) * 8;       // 0,8,16,24
    const short* pA = Ab + (size_t)(m0 + row) * lda + kc;
    const short* pB = Bb + (size_t)(n0 + row) * ldb + kc;
    const size_t stA = (size_t)64 * lda;
    const size_t stB = (size_t)64 * ldb;

    floatx4 acc[4][WJ];
    #pragma unroll
    for (int i = 0; i < 4; ++i)
        #pragma unroll
        for (int j = 0; j < WJ; ++j) acc[i][j] = (floatx4)(0.f);

    auto stage = [&](int bi) {
        async16(pA,       &As[bi][row][kc]);
        async16(pA + stA, &As[bi][row + 64][kc]);
        async16(pB,       &Bs[bi][row][kc]);
        if (WJ == 4) async16(pB + stB, &Bs[bi][row + 64][kc]);
        pA += BK; pB += BK;              // strength-reduced advance
    };

    const int NK = K / BK;
    stage(0);
    __syncthreads();

    for (int it = 0; it < NK; ++it) {
        const int bi = it & 1;
        if (it + 1 < NK) stage(bi ^ 1);  // async prefetch into other buffer

        bf16x8 af[4], bfr[WJ];
        #pragma unroll
        for (int i = 0; i < 4; ++i)
            af[i] = *(const bf16x8*)&As[bi][wr * 64 + i * 16 + lr][lq * 8];
        #pragma unroll
        for (int j = 0; j < WJ; ++j)
            bfr[j] = *(const bf16x8*)&Bs[bi][wc * (16 * WJ) + j * 16 + lr][lq * 8];
        #pragma unroll
        for (int i = 0; i < 4; ++i)
            #pragma unroll
            for (int j = 0; j < WJ; ++j)
                acc[i][j] = __builtin_amdgcn_mfma_f32_16x16x32_bf16(
                    af[i], bfr[j], acc[i][j], 0, 0, 0);

        if (it + 1 < NK) __syncthreads();
    }

    // D layout: col = lane&15, row = (lane>>4)*4 + r  [m89-verified]
    #pragma unroll
    for (int j = 0; j < WJ; ++j) {
        const int gn = n0 + wc * (16 * WJ) + j * 16 + lr;
        const float bv = bias ? bias[gn] : 0.f;
        #pragma unroll
        for (int i = 0; i < 4; ++i) {
            #pragma unroll
            for (int r = 0; r < 4; ++r) {
                const int gm = m0 + wr * 64 + i * 16 + lq * 4 + r;
                const float v = acc[i][j][r] * scale + bv;
                if (OUT_BF16) {
                    ((short*)Cb)[(size_t)gm * ldc + gn] = f2bf(v);
                } else {
                    ((float*)Cb)[(size_t)gm * ldc + gn] = v;
                }
            }
        }
    }
}

// ---------------------------------------------------------------------------
// All 3 projections, one 1536-block launch. xcd = b&7; z phases (q,k,v) are
// dispatch-ordered so each XCD's live working set is ~4 MB (8 A-panels + W).
// ---------------------------------------------------------------------------
__global__ __launch_bounds__(256)
void proj_qkv(const short* __restrict__ xq, const short* __restrict__ xk,
              const short* __restrict__ xv,
              const short* __restrict__ Wq_, const short* __restrict__ Wk_,
              const short* __restrict__ Wv_,
              const float* __restrict__ bq_, const float* __restrict__ bk_,
              const float* __restrict__ bv_,
              short* __restrict__ q, short* __restrict__ k, short* __restrict__ vp)
{
    const int b   = blockIdx.x;
    const int xcd = b & 7;
    const int i   = b >> 3;          // 0..191
    const int z   = i >> 6;          // 0..2  (slowest-varying: phases)
    const int mm  = (i >> 3) & 7;
    const int nn  = i & 7;
    const short* X = (z == 0) ? xq : (z == 1) ? xk : xv;
    const short* W = (z == 0) ? Wq_ : (z == 1) ? Wk_ : Wv_;
    const float* bb = (z == 0) ? bq_ : (z == 1) ? bk_ : bv_;
    short* O = (z == 0) ? q : (z == 1) ? k : vp;
    gemm_core<true, 4>(X, DIMN, W, DIMN, (void*)O, DIMN, bb, DIMN, 1.f,
                       (xcd * 8 + mm) * BM, nn * 128);
}

// scores: 1024 blocks. XCD x -> batch x>>1, m-half x&1.
__global__ __launch_bounds__(256)
void gemm_scores(const short* __restrict__ q, const short* __restrict__ k,
                 short* __restrict__ S, float scale)
{
    const int b   = blockIdx.x;
    const int xcd = b & 7;
    const int i   = b >> 3;          // 0..127
    const int bz  = xcd >> 1;
    const int mh  = xcd & 1;
    const int mm  = i >> 4;          // 0..7
    const int nn  = i & 15;          // 0..15
    gemm_core<true, 4>(q + (size_t)bz * SEQ * DIMN, DIMN,
                       k + (size_t)bz * SEQ * DIMN, DIMN,
                       (void*)(S + (size_t)bz * SEQ * SEQ), SEQ,
                       nullptr, DIMN, scale,
                       (mh * 8 + mm) * BM, nn * 128);
}

// PV: 128x64 tiles -> 1024 blocks (4/CU). Same batch->XCD map as scores/softmax.
__global__ __launch_bounds__(256)
void gemm_pv(const short* __restrict__ P, const short* __restrict__ vt,
             float* __restrict__ O)
{
    const int b   = blockIdx.x;
    const int xcd = b & 7;
    const int i   = b >> 3;          // 0..127
    const int bz  = xcd >> 1;
    const int mh  = xcd & 1;
    const int mm  = i >> 4;          // 0..7
    const int nn  = i & 15;          // 0..15
    gemm_core<false, 2>(P  + (size_t)bz * SEQ * SEQ,  SEQ,
                        vt + (size_t)bz * DIMN * SEQ, SEQ,
                        (void*)(O + (size_t)bz * SEQ * DIMN), DIMN,
                        nullptr, SEQ, 1.f,
                        (mh * 8 + mm) * BM, nn * 64);
}

// ---------------------------------------------------------------------------
// fp32 -> bf16 bulk convert, up to 3 arrays per launch (blockIdx.z picks).
// ---------------------------------------------------------------------------
__global__ __launch_bounds__(256)
void cvt_tri(const float* __restrict__ in0, short* __restrict__ out0,
             const float* __restrict__ in1, short* __restrict__ out1,
             const float* __restrict__ in2, short* __restrict__ out2, int n8)
{
    const int z = blockIdx.z;
    const float* in = (z == 0) ? in0 : (z == 1) ? in1 : in2;
    short* out      = (z == 0) ? out0 : (z == 1) ? out1 : out2;
    const int i = blockIdx.x * 256 + threadIdx.x;
    if (i >= n8) return;
    const float4 a0 = ((const float4*)in)[(size_t)i * 2];
    const float4 a1 = ((const float4*)in)[(size_t)i * 2 + 1];
    const float v[8] = {a0.x, a0.y, a0.z, a0.w, a1.x, a1.y, a1.z, a1.w};
    bf16x8 o;
    #pragma unroll
    for (int j = 0; j < 8; ++j) o[j] = f2bf(v[j]);
    *(bf16x8*)(out + (size_t)i * 8) = o;
}

// ---------------------------------------------------------------------------
// Effective biases: out[n] = b[n] + dot(ctx, W[n,:]) (ctx only for q,k).
// ---------------------------------------------------------------------------
__global__ __launch_bounds__(256)
void bias3(const float* __restrict__ Wq, const float* __restrict__ Wk,
           const float* __restrict__ Wv,
           const float* __restrict__ bq, const float* __restrict__ bk,
           const float* __restrict__ bv,
           const float* __restrict__ ctx,
           float* __restrict__ oq, float* __restrict__ ok, float* __restrict__ ov)
{
    const int z = blockIdx.y;
    const float* W = (z == 0) ? Wq : (z == 1) ? Wk : Wv;
    const float* b = (z == 0) ? bq : (z == 1) ? bk : bv;
    float*       o = (z == 0) ? oq : (z == 1) ? ok : ov;
    const int n    = blockIdx.x * 4 + (threadIdx.x >> 6);
    const int lane = threadIdx.x & 63;
    float s = 0.f;
    if (z < 2) {
        const float* row = W + (size_t)n * DIMN;
        for (int k = lane * 4; k < DIMN; k += 256) {
            const float4 x = *(const float4*)(row + k);
            const float4 c = *(const float4*)(ctx + k);
            s += x.x * c.x + x.y * c.y + x.z * c.z + x.w * c.w;
        }
        #pragma unroll
        for (int off = 32; off > 0; off >>= 1) s += __shfl_xor(s, off);
    }
    if (lane == 0) o[n] = b[n] + s;
}

// ---------------------------------------------------------------------------
// bf16 transpose: in [B][S][D] -> out [B][D][S], 64x64 LDS tiles.
// ---------------------------------------------------------------------------
__global__ __launch_bounds__(256)
void transpose_v(const short* __restrict__ in, short* __restrict__ out)
{
    __shared__ short t[64][68];
    const int b  = blockIdx.z;
    const int d0 = blockIdx.x * 64;
    const int s0 = blockIdx.y * 64;
    const int r  = threadIdx.x >> 3;
    const int c  = (threadIdx.x & 7) * 8;
    #pragma unroll
    for (int h = 0; h < 2; ++h) {
        const int s = r + h * 32;
        bf16x8 v = *(const bf16x8*)(in + ((size_t)b * SEQ + s0 + s) * DIMN + d0 + c);
        #pragma unroll
        for (int j = 0; j < 8; ++j) t[c + j][s] = v[j];
    }
    __syncthreads();
    #pragma unroll
    for (int h = 0; h < 2; ++h) {
        const int d = r + h * 32;
        bf16x8 v;
        #pragma unroll
        for (int j = 0; j < 8; ++j) v[j] = t[d][c + j];
        *(bf16x8*)(out + ((size_t)b * DIMN + d0 + d) * SEQ + s0 + c) = v;
    }
}

// ---------------------------------------------------------------------------
// Row softmax, in place on bf16 [M1 rows][SEQ]. XCD-aligned with scores'
// writer (batch bz lives on XCDs {2bz, 2bz+1}) so reads hit that L2.
// ---------------------------------------------------------------------------
__global__ __launch_bounds__(256)
void softmax_kernel(short* __restrict__ P)
{
    const int bid = blockIdx.x;
    const int xcd = bid & 7;
    const int i   = bid >> 3;            // 0..1023
    const int row = (xcd >> 1) * SEQ + (xcd & 1) * 1024 + i;
    short* p = P + (size_t)row * SEQ;
    const int t    = threadIdx.x;
    const int lane = t & 63;
    const int wave = t >> 6;
    __shared__ float red[8];

    bf16x8 raw = *(const bf16x8*)(p + t * 8);
    float v[8];
    float mx = -1e30f;
    #pragma unroll
    for (int j = 0; j < 8; ++j) { v[j] = bf2f(raw[j]); mx = fmaxf(mx, v[j]); }
    #pragma unroll
    for (int off = 32; off > 0; off >>= 1) mx = fmaxf(mx, __shfl_xor(mx, off));
    if (lane == 0) red[wave] = mx;
    __syncthreads();
    mx = fmaxf(fmaxf(red[0], red[1]), fmaxf(red[2], red[3]));

    float e[8], s = 0.f;
    #pragma unroll
    for (int j = 0; j < 8; ++j) { e[j] = __expf(v[j] - mx); s += e[j]; }
    #pragma unroll
    for (int off = 32; off > 0; off >>= 1) s += __shfl_xor(s, off);
    if (lane == 0) red[4 + wave] = s;
    __syncthreads();
    s = red[4] + red[5] + red[6] + red[7];
    const float inv = 1.f / s;

    bf16x8 o;
    #pragma unroll
    for (int j = 0; j < 8; ++j) o[j] = f2bf(e[j] * inv);
    *(bf16x8*)(p + t * 8) = o;
}

// ---------------------------------------------------------------------------
extern "C" void kernel_launch(void* const* d_in, const int* in_sizes, int n_in,
                              void* d_out, int out_size, void* d_ws, size_t ws_size,
                              hipStream_t stream)
{
    const float* query = (const float*)d_in[0];
    const float* key_  = (const float*)d_in[1];
    const float* value = (const float*)d_in[2];
    const float* ctx   = (const float*)d_in[3];
    const float* Wq    = (const float*)d_in[4];
    const float* bq    = (const float*)d_in[5];
    const float* Wk    = (const float*)d_in[6];
    const float* bk    = (const float*)d_in[7];
    const float* Wv    = (const float*)d_in[8];
    const float* bv    = (const float*)d_in[9];

    // Workspace (80 MB) + d_out (32 MB) doubling as scratch for xv/vp:
    //   ws:  xq [0,16) xk [16,32)  -> dead after proj -> S_b [0,32)
    //        q_b [32,48) k_b [48,64)
    //        W3 [64,70) + biases    -> dead after proj -> v_t [64,80)
    //   d_out: xv [0,16) vp [16,32) -> dead after transpose -> final output
    char* ws = (char*)d_ws;
    char* od = (char*)d_out;
    const size_t MB = 1ull << 20;
    short* xq   = (short*)(ws);
    short* xk   = (short*)(ws + 16 * MB);
    short* q_b  = (short*)(ws + 32 * MB);
    short* k_b  = (short*)(ws + 48 * MB);
    short* Wq_b = (short*)(ws + 64 * MB);
    short* Wk_b = (short*)(ws + 66 * MB);
    short* Wv_b = (short*)(ws + 68 * MB);
    float* bq_e = (float*)(ws + 70 * MB);
    float* bk_e = (float*)(ws + 70 * MB + 4096);
    float* bv_e = (float*)(ws + 70 * MB + 8192);
    short* S_b  = (short*)(ws);
    short* v_t  = (short*)(ws + 64 * MB);
    short* xv   = (short*)(od);
    short* vp   = (short*)(od + 16 * MB);

    dim3 blk(256);
    const int W8 = DIMN * DIMN / 8;  // 131072
    const int X8 = M1 * DIMN / 8;    // 1048576

    cvt_tri<<<dim3(W8 / 256, 1, 3), blk, 0, stream>>>(Wq, Wq_b, Wk, Wk_b, Wv, Wv_b, W8);
    bias3<<<dim3(DIMN / 4, 3), blk, 0, stream>>>(Wq, Wk, Wv, bq, bk, bv, ctx,
                                                 bq_e, bk_e, bv_e);
    cvt_tri<<<dim3(X8 / 256, 1, 3), blk, 0, stream>>>(query, xq, key_, xk, value, xv, X8);

    proj_qkv<<<dim3(1536), blk, 0, stream>>>(xq, xk, xv, Wq_b, Wk_b, Wv_b,
                                             bq_e, bk_e, bv_e, q_b, k_b, vp);
    transpose_v<<<dim3(DIMN / 64, SEQ / 64, BATCH), blk, 0, stream>>>(vp, v_t);

    const float scale = 1.0f / 32.0f; // DIMN^-0.5
    gemm_scores<<<dim3(1024), blk, 0, stream>>>(q_b, k_b, S_b, scale);

    softmax_kernel<<<dim3(M1), blk, 0, stream>>>(S_b);

    gemm_pv<<<dim3(1024), blk, 0, stream>>>(S_b, v_t, (float*)d_out);
}